// Round 1
// baseline (563.482 us; speedup 1.0000x reference)
//
#include <hip/hip_runtime.h>
#include <math.h>

#define D      256
#define N2     8192
#define NHALF  4096
#define BM     64
#define BN     64
#define KC     32
#define LSTR   68   // LDS leading stride in floats: 68*4=272 bytes, 16B-aligned rows, mild write conflicts only

// ---------------- kernel 1: row-normalize concat(emb_i, emb_j) -> z ----------------
__global__ __launch_bounds__(256) void nrm_kernel(const float* __restrict__ a,
                                                  const float* __restrict__ b,
                                                  float* __restrict__ z) {
    const int wave = threadIdx.x >> 6;
    const int lane = threadIdx.x & 63;
    const int row  = blockIdx.x * 4 + wave;
    const float* src = (row < NHALF) ? (a + (size_t)row * D) : (b + (size_t)(row - NHALF) * D);
    float4 v = ((const float4*)src)[lane];
    float ss = v.x * v.x + v.y * v.y + v.z * v.z + v.w * v.w;
    #pragma unroll
    for (int off = 32; off; off >>= 1) ss += __shfl_xor(ss, off, 64);
    const float inv = 1.0f / fmaxf(sqrtf(ss), 1e-8f);
    v.x *= inv; v.y *= inv; v.z *= inv; v.w *= inv;
    ((float4*)(z + (size_t)row * D))[lane] = v;
}

// ---------------- kernel 2: zero the per-row denom accumulators ----------------
__global__ void zero_kernel(float* __restrict__ p, int n) {
    int i = blockIdx.x * blockDim.x + threadIdx.x;
    if (i < n) p[i] = 0.0f;
}

// ---------------- kernel 3: tiled sim + exp-sum + positive extraction ----------------
// grid: (N2/BM = 128, 8). Block bx owns rows [bx*64, bx*64+64); chunk by owns cols [by*1024, by*1024+1024).
__global__ __launch_bounds__(256) void sim_kernel(const float* __restrict__ z,
                                                  float* __restrict__ g_denom,
                                                  float* __restrict__ g_pos) {
    __shared__ float As[KC * LSTR];
    __shared__ float Bs[KC * LSTR];

    const int tid = threadIdx.x;
    const int tx  = tid & 15;          // column micro-tile index
    const int ty  = tid >> 4;          // row micro-tile index
    const int r0  = blockIdx.x * BM;
    const int cb  = blockIdx.y * 1024;

    float dsum[4] = {0.f, 0.f, 0.f, 0.f};

    for (int tile = 0; tile < 16; ++tile) {
        const int c0 = cb + tile * BN;
        float acc[4][4] = {};

        for (int kc = 0; kc < D; kc += KC) {
            __syncthreads();   // previous compute done before overwrite
            // stage A-tile (rows) and B-tile (cols), transposed to [k][m] layout
            #pragma unroll
            for (int rep = 0; rep < 2; ++rep) {
                const int f  = tid + rep * 256;      // float4 id in [0,512)
                const int r  = f >> 3;               // tile row 0..63
                const int kg = (f & 7) * 4;          // k offset 0,4,..,28
                float4 va = *(const float4*)&z[(size_t)(r0 + r) * D + kc + kg];
                As[(kg + 0) * LSTR + r] = va.x;
                As[(kg + 1) * LSTR + r] = va.y;
                As[(kg + 2) * LSTR + r] = va.z;
                As[(kg + 3) * LSTR + r] = va.w;
                float4 vb = *(const float4*)&z[(size_t)(c0 + r) * D + kc + kg];
                Bs[(kg + 0) * LSTR + r] = vb.x;
                Bs[(kg + 1) * LSTR + r] = vb.y;
                Bs[(kg + 2) * LSTR + r] = vb.z;
                Bs[(kg + 3) * LSTR + r] = vb.w;
            }
            __syncthreads();

            #pragma unroll
            for (int k = 0; k < KC; ++k) {
                float4 a4 = *(const float4*)&As[k * LSTR + 4 * ty];
                float4 b4 = *(const float4*)&Bs[k * LSTR + 4 * tx];
                const float av[4] = {a4.x, a4.y, a4.z, a4.w};
                const float bv[4] = {b4.x, b4.y, b4.z, b4.w};
                #pragma unroll
                for (int i = 0; i < 4; ++i)
                    #pragma unroll
                    for (int j = 0; j < 4; ++j)
                        acc[i][j] += av[i] * bv[j];
            }
        }

        // epilogue: exp / diagonal mask / positive capture
        #pragma unroll
        for (int i = 0; i < 4; ++i) {
            const int row = r0 + 4 * ty + i;
            const int prt = row ^ NHALF;
            #pragma unroll
            for (int j = 0; j < 4; ++j) {
                const int col = c0 + 4 * tx + j;
                const float s = acc[i][j];
                const float e = __expf(2.0f * s);
                dsum[i] += (col == row) ? 0.0f : e;
                if (col == prt) g_pos[row] = s;
            }
        }
    }

    // block-level reduce of dsum into 64 per-row slots, then one global atomic per row
    __syncthreads();
    if (tid < BM) As[tid] = 0.0f;
    __syncthreads();
    #pragma unroll
    for (int i = 0; i < 4; ++i) atomicAdd(&As[4 * ty + i], dsum[i]);
    __syncthreads();
    if (tid < BM) atomicAdd(&g_denom[r0 + tid], As[tid]);
}

// ---------------- kernel 4: finalize -> scalar loss ----------------
__global__ __launch_bounds__(256) void fin_kernel(const float* __restrict__ g_denom,
                                                  const float* __restrict__ g_pos,
                                                  float* __restrict__ out) {
    const int tid = threadIdx.x;
    float local = 0.0f;
    for (int k = tid; k < N2; k += 256)
        local += logf(g_denom[k]) - 2.0f * g_pos[k];
    #pragma unroll
    for (int off = 32; off; off >>= 1) local += __shfl_xor(local, off, 64);
    __shared__ float sw[4];
    if ((tid & 63) == 0) sw[tid >> 6] = local;
    __syncthreads();
    if (tid == 0) out[0] = (sw[0] + sw[1] + sw[2] + sw[3]) / (float)N2;
}

extern "C" void kernel_launch(void* const* d_in, const int* in_sizes, int n_in,
                              void* d_out, int out_size, void* d_ws, size_t ws_size,
                              hipStream_t stream) {
    const float* emb_i = (const float*)d_in[0];
    const float* emb_j = (const float*)d_in[1];

    float* z       = (float*)d_ws;                                   // 8192*256 fp32 = 8 MB
    float* g_denom = (float*)((char*)d_ws + (size_t)N2 * D * 4);     // 8192 fp32
    float* g_pos   = g_denom + N2;                                   // 8192 fp32
    float* out     = (float*)d_out;

    nrm_kernel<<<N2 / 4, 256, 0, stream>>>(emb_i, emb_j, z);
    zero_kernel<<<N2 / 256, 256, 0, stream>>>(g_denom, N2);
    dim3 grid(N2 / BM, 8);
    sim_kernel<<<grid, 256, 0, stream>>>(z, g_denom, g_pos);
    fin_kernel<<<1, 256, 0, stream>>>(g_denom, g_pos, out);
}

// Round 2
// 157.134 us; speedup vs baseline: 3.5860x; 3.5860x over previous
//
#include <hip/hip_runtime.h>
#include <hip/hip_bf16.h>
#include <math.h>

#define D      256
#define N2     8192
#define NHALF  4096
#define TM     128    // block tile (rows == cols)
#define BK     32     // K-chunk per LDS stage

typedef __bf16 bf16x8_t __attribute__((ext_vector_type(8)));
typedef __bf16 bf16x4_t __attribute__((ext_vector_type(4)));
typedef float  f32x4_t  __attribute__((ext_vector_type(4)));

// ---------------- kernel 1: row-normalize concat(emb_i, emb_j) -> zb (bf16) ----------------
__global__ __launch_bounds__(256) void nrm_kernel(const float* __restrict__ a,
                                                  const float* __restrict__ b,
                                                  __bf16* __restrict__ zb) {
    const int wave = threadIdx.x >> 6;
    const int lane = threadIdx.x & 63;
    const int row  = blockIdx.x * 4 + wave;
    const float* src = (row < NHALF) ? (a + (size_t)row * D) : (b + (size_t)(row - NHALF) * D);
    float4 v = ((const float4*)src)[lane];
    float ss = v.x * v.x + v.y * v.y + v.z * v.z + v.w * v.w;
    #pragma unroll
    for (int off = 32; off; off >>= 1) ss += __shfl_xor(ss, off, 64);
    const float inv = 1.0f / fmaxf(sqrtf(ss), 1e-8f);
    bf16x4_t o;
    o[0] = (__bf16)(v.x * inv);
    o[1] = (__bf16)(v.y * inv);
    o[2] = (__bf16)(v.z * inv);
    o[3] = (__bf16)(v.w * inv);
    *(bf16x4_t*)(zb + (size_t)row * D + lane * 4) = o;
}

// ---------------- kernel 2: zero the per-row denom accumulators ----------------
__global__ void zero_kernel(float* __restrict__ p, int n) {
    int i = blockIdx.x * blockDim.x + threadIdx.x;
    if (i < n) p[i] = 0.0f;
}

// ---------------- kernel 3: exact fp32 positives (one wave per row pair) ----------------
__global__ __launch_bounds__(256) void pos_kernel(const float* __restrict__ a,
                                                  const float* __restrict__ b,
                                                  float* __restrict__ g_pos) {
    const int w    = blockIdx.x * 4 + (threadIdx.x >> 6);   // row in [0, NHALF)
    const int lane = threadIdx.x & 63;
    float4 x = ((const float4*)(a + (size_t)w * D))[lane];
    float4 y = ((const float4*)(b + (size_t)w * D))[lane];
    float sxx = x.x * x.x + x.y * x.y + x.z * x.z + x.w * x.w;
    float syy = y.x * y.x + y.y * y.y + y.z * y.z + y.w * y.w;
    float sxy = x.x * y.x + x.y * y.y + x.z * y.z + x.w * y.w;
    #pragma unroll
    for (int off = 32; off; off >>= 1) {
        sxx += __shfl_xor(sxx, off, 64);
        syy += __shfl_xor(syy, off, 64);
        sxy += __shfl_xor(sxy, off, 64);
    }
    if (lane == 0) {
        const float p = sxy / (fmaxf(sqrtf(sxx), 1e-8f) * fmaxf(sqrtf(syy), 1e-8f));
        g_pos[w]         = p;
        g_pos[w + NHALF] = p;
    }
}

// ---------------- kernel 4: MFMA sim tile + exp-rowsum + diagonal mask ----------------
// grid (64, 64): blockIdx.y = row tile, blockIdx.x = col tile. 256 thr = 4 waves, 64x64 each.
__global__ __launch_bounds__(256) void sim_kernel(const __bf16* __restrict__ zb,
                                                  float* __restrict__ g_denom) {
    __shared__ __bf16 As[TM * BK];   // [row][k], 64 B rows -> 8 KB
    __shared__ __bf16 Bs[TM * BK];   // [col][k]

    const int tid  = threadIdx.x;
    const int w    = tid >> 6;
    const int l    = tid & 63;
    const int r0   = blockIdx.y * TM;
    const int c0   = blockIdx.x * TM;
    const int wrow = (w & 1) * 64;
    const int wcol = (w >> 1) * 64;

    f32x4_t acc[4][4] = {};

    for (int kc = 0; kc < D; kc += BK) {
        __syncthreads();   // all waves done reading LDS from previous stage
        #pragma unroll
        for (int p = 0; p < 2; ++p) {
            const int r   = 32 * w + 16 * p + (l >> 2);     // tile row/col index
            const int cof = (l & 3) * 8;                    // k offset within BK (elements)
            const __bf16* ga = zb + (size_t)(r0 + r) * D + kc + cof;
            const __bf16* gb = zb + (size_t)(c0 + r) * D + kc + cof;
            __builtin_amdgcn_global_load_lds(
                (const __attribute__((address_space(1))) void*)ga,
                (__attribute__((address_space(3))) void*)(As + (32 * w + 16 * p) * BK),
                16, 0, 0);
            __builtin_amdgcn_global_load_lds(
                (const __attribute__((address_space(1))) void*)gb,
                (__attribute__((address_space(3))) void*)(Bs + (32 * w + 16 * p) * BK),
                16, 0, 0);
        }
        __syncthreads();   // drains vmcnt (global_load_lds) + lgkm before use

        bf16x8_t af[4], bfr[4];
        const int kq = (l >> 4) * 8;   // k-offset held by this lane group
        #pragma unroll
        for (int mi = 0; mi < 4; ++mi)
            af[mi] = *(const bf16x8_t*)(As + (wrow + 16 * mi + (l & 15)) * BK + kq);
        #pragma unroll
        for (int nj = 0; nj < 4; ++nj)
            bfr[nj] = *(const bf16x8_t*)(Bs + (wcol + 16 * nj + (l & 15)) * BK + kq);
        #pragma unroll
        for (int mi = 0; mi < 4; ++mi)
            #pragma unroll
            for (int nj = 0; nj < 4; ++nj)
                acc[mi][nj] = __builtin_amdgcn_mfma_f32_16x16x32_bf16(af[mi], bfr[nj], acc[mi][nj], 0, 0, 0);
    }

    // epilogue: exp(2s), mask diagonal, reduce rows, one atomic per row per wave
    const int lrow4 = (l >> 4) * 4;   // C/D: row = (lane>>4)*4 + reg, col = lane&15
    const int lcol  = l & 15;
    #pragma unroll
    for (int mi = 0; mi < 4; ++mi) {
        const int rowb = r0 + wrow + 16 * mi + lrow4;
        f32x4_t rs = {0.f, 0.f, 0.f, 0.f};
        #pragma unroll
        for (int nj = 0; nj < 4; ++nj) {
            const int col = c0 + wcol + 16 * nj + lcol;
            #pragma unroll
            for (int t = 0; t < 4; ++t) {
                const float e = __expf(2.0f * acc[mi][nj][t]);
                rs[t] += (col == rowb + t) ? 0.0f : e;
            }
        }
        #pragma unroll
        for (int off = 1; off < 16; off <<= 1) {
            #pragma unroll
            for (int t = 0; t < 4; ++t) {
                float v = rs[t];
                rs[t] = v + __shfl_xor(v, off, 64);
            }
        }
        if (lcol == 0) {
            #pragma unroll
            for (int t = 0; t < 4; ++t) atomicAdd(&g_denom[rowb + t], rs[t]);
        }
    }
}

// ---------------- kernel 5: finalize -> scalar loss ----------------
__global__ __launch_bounds__(256) void fin_kernel(const float* __restrict__ g_denom,
                                                  const float* __restrict__ g_pos,
                                                  float* __restrict__ out) {
    const int tid = threadIdx.x;
    float local = 0.0f;
    for (int k = tid; k < N2; k += 256)
        local += logf(g_denom[k]) - 2.0f * g_pos[k];
    #pragma unroll
    for (int off = 32; off; off >>= 1) local += __shfl_xor(local, off, 64);
    __shared__ float sw[4];
    if ((tid & 63) == 0) sw[tid >> 6] = local;
    __syncthreads();
    if (tid == 0) out[0] = (sw[0] + sw[1] + sw[2] + sw[3]) / (float)N2;
}

extern "C" void kernel_launch(void* const* d_in, const int* in_sizes, int n_in,
                              void* d_out, int out_size, void* d_ws, size_t ws_size,
                              hipStream_t stream) {
    const float* emb_i = (const float*)d_in[0];
    const float* emb_j = (const float*)d_in[1];

    __bf16* zb     = (__bf16*)d_ws;                                  // 8192*256 bf16 = 4 MB
    float*  g_denom = (float*)((char*)d_ws + (size_t)N2 * D * 2);    // 8192 fp32
    float*  g_pos   = g_denom + N2;                                  // 8192 fp32
    float*  out     = (float*)d_out;

    nrm_kernel<<<N2 / 4, 256, 0, stream>>>(emb_i, emb_j, zb);
    zero_kernel<<<N2 / 256, 256, 0, stream>>>(g_denom, N2);
    pos_kernel<<<NHALF / 4, 256, 0, stream>>>(emb_i, emb_j, g_pos);
    dim3 grid(N2 / TM, N2 / TM);
    sim_kernel<<<grid, 256, 0, stream>>>(zb, g_denom);
    fin_kernel<<<1, 256, 0, stream>>>(g_denom, g_pos, out);
}

// Round 3
// 143.284 us; speedup vs baseline: 3.9326x; 1.0967x over previous
//
#include <hip/hip_runtime.h>
#include <hip/hip_bf16.h>
#include <math.h>

#define D      256
#define N2     8192
#define NHALF  4096
#define TB     256    // block tile (rows and cols)
#define NT     32     // N2 / TB tiles per dim

typedef __bf16 bf16x8_t __attribute__((ext_vector_type(8)));
typedef __bf16 bf16x4_t __attribute__((ext_vector_type(4)));
typedef float  f32x4_t  __attribute__((ext_vector_type(4)));

// ---------------- kernel 1: fused normalize + positives + denom-zero ----------------
// One wave per row pair (w, w+NHALF). Grid 1024 x 256 thr.
__global__ __launch_bounds__(256) void prep_kernel(const float* __restrict__ a,
                                                   const float* __restrict__ b,
                                                   __bf16* __restrict__ zb,
                                                   float* __restrict__ g_pos,
                                                   float* __restrict__ g_denom) {
    const int tid = threadIdx.x;
    const int gt  = blockIdx.x * 256 + tid;
    if (gt < N2) g_denom[gt] = 0.0f;          // zero accumulators (prep precedes sim on stream)

    const int w = blockIdx.x * 4 + (tid >> 6);  // pair row in [0, NHALF)
    const int l = tid & 63;
    float4 x = ((const float4*)(a + (size_t)w * D))[l];
    float4 y = ((const float4*)(b + (size_t)w * D))[l];
    float sxx = x.x * x.x + x.y * x.y + x.z * x.z + x.w * x.w;
    float syy = y.x * y.x + y.y * y.y + y.z * y.z + y.w * y.w;
    float sxy = x.x * y.x + x.y * y.y + x.z * y.z + x.w * y.w;
    #pragma unroll
    for (int off = 32; off; off >>= 1) {
        sxx += __shfl_xor(sxx, off, 64);
        syy += __shfl_xor(syy, off, 64);
        sxy += __shfl_xor(sxy, off, 64);
    }
    const float rx = 1.0f / fmaxf(sqrtf(sxx), 1e-8f);
    const float ry = 1.0f / fmaxf(sqrtf(syy), 1e-8f);

    bf16x4_t ox, oy;
    ox[0] = (__bf16)(x.x * rx); ox[1] = (__bf16)(x.y * rx);
    ox[2] = (__bf16)(x.z * rx); ox[3] = (__bf16)(x.w * rx);
    oy[0] = (__bf16)(y.x * ry); oy[1] = (__bf16)(y.y * ry);
    oy[2] = (__bf16)(y.z * ry); oy[3] = (__bf16)(y.w * ry);
    *(bf16x4_t*)(zb + (size_t)w * D + l * 4)           = ox;
    *(bf16x4_t*)(zb + (size_t)(w + NHALF) * D + l * 4) = oy;

    if (l == 0) {
        const float p = sxy * rx * ry;   // exact fp32 positive similarity
        g_pos[w]         = p;
        g_pos[w + NHALF] = p;
    }
}

// ---------------- kernel 2: register-resident-A symmetric sim + exp row/col sums ----
// Lower-triangle tile grid: 528 blocks, 4 waves each. Wave owns 64 rows x K=256 in
// registers (A-frags); B-frags streamed directly from L2 per 16-col strip. No LDS,
// no barriers. mfma(bf, af) puts the ROW index in lane&15 -> cheap row reduction.
__global__ __launch_bounds__(256, 2) void sim_kernel(const __bf16* __restrict__ zb,
                                                     float* __restrict__ g_denom) {
    const int tid    = threadIdx.x;
    const int w      = tid >> 6;
    const int l      = tid & 63;
    const int lane15 = l & 15;
    const int quad   = l >> 4;

    // decode lower-triangle block id -> (br, bc), bc <= br
    const int bid = blockIdx.x;
    int br = (int)((sqrtf(8.0f * (float)bid + 1.0f) - 1.0f) * 0.5f);
    while ((br + 1) * (br + 2) / 2 <= bid) ++br;
    while (br * (br + 1) / 2 > bid) --br;
    const int bc = bid - br * (br + 1) / 2;

    const int r0 = br * TB + w * 64;   // this wave's 64 rows
    const int c0 = bc * TB;            // block's 256 cols

    // load A fragments: 64 rows x 256 K, held for the whole block (128 VGPRs)
    bf16x8_t af[4][8];
    {
        const __bf16* abase = zb + (size_t)(r0 + lane15) * D + quad * 8;
        #pragma unroll
        for (int mi = 0; mi < 4; ++mi)
            #pragma unroll
            for (int kc = 0; kc < 8; ++kc)
                af[mi][kc] = *(const bf16x8_t*)(abase + (size_t)mi * 16 * D + kc * 32);
    }

    float rs[4] = {0.f, 0.f, 0.f, 0.f};
    const bool diag      = (br == bc);
    const int  nstrip    = diag ? (4 * w + 4) : 16;
    const int  mask_from = diag ? (4 * w)     : 16;

    for (int s = 0; s < nstrip; ++s) {
        const int cs = c0 + s * 16;
        bf16x8_t bfr[8];
        const __bf16* bbase = zb + (size_t)(cs + lane15) * D + quad * 8;
        #pragma unroll
        for (int kc = 0; kc < 8; ++kc)
            bfr[kc] = *(const bf16x8_t*)(bbase + kc * 32);

        f32x4_t acc[4] = {{0.f,0.f,0.f,0.f},{0.f,0.f,0.f,0.f},{0.f,0.f,0.f,0.f},{0.f,0.f,0.f,0.f}};
        #pragma unroll
        for (int kc = 0; kc < 8; ++kc)
            #pragma unroll
            for (int mi = 0; mi < 4; ++mi)
                acc[mi] = __builtin_amdgcn_mfma_f32_16x16x32_bf16(bfr[kc], af[mi][kc], acc[mi], 0, 0, 0);
        // acc[mi] holds S^T frag: row = r0+16*mi+lane15, col = cs+quad*4+reg

        const bool masked = (s >= mask_from);   // wave-uniform
        float cp[4] = {0.f, 0.f, 0.f, 0.f};
        #pragma unroll
        for (int mi = 0; mi < 4; ++mi) {
            const int row = r0 + 16 * mi + lane15;
            float rpart = 0.f;
            #pragma unroll
            for (int t = 0; t < 4; ++t) {
                const int n = cs + quad * 4 + t;
                float e = __expf(2.0f * acc[mi][t]);
                if (masked) e = (n < row) ? e : 0.0f;   // diagonal tile: strict lower only
                rpart += e;
                cp[t] += e;
            }
            rs[mi] += rpart;
        }
        // column sums: reduce over the 16 row-lanes, one atomic instr (lanes 0,16,32,48)
        #pragma unroll
        for (int off = 1; off < 16; off <<= 1) {
            #pragma unroll
            for (int t = 0; t < 4; ++t) cp[t] += __shfl_xor(cp[t], off, 64);
        }
        if (lane15 == 0) {
            #pragma unroll
            for (int t = 0; t < 4; ++t) atomicAdd(&g_denom[cs + quad * 4 + t], cp[t]);
        }
    }

    // row sums: reduce over the 4 quad groups, one atomic instr per mi
    #pragma unroll
    for (int mi = 0; mi < 4; ++mi) {
        rs[mi] += __shfl_xor(rs[mi], 16, 64);
        rs[mi] += __shfl_xor(rs[mi], 32, 64);
    }
    if (l < 16) {
        #pragma unroll
        for (int mi = 0; mi < 4; ++mi)
            atomicAdd(&g_denom[r0 + 16 * mi + l], rs[mi]);
    }
}

// ---------------- kernel 3: finalize -> scalar loss ----------------
__global__ __launch_bounds__(256) void fin_kernel(const float* __restrict__ g_denom,
                                                  const float* __restrict__ g_pos,
                                                  float* __restrict__ out) {
    const int tid = threadIdx.x;
    float local = 0.0f;
    for (int k = tid; k < N2; k += 256)
        local += logf(g_denom[k]) - 2.0f * g_pos[k];
    #pragma unroll
    for (int off = 32; off; off >>= 1) local += __shfl_xor(local, off, 64);
    __shared__ float sw[4];
    if ((tid & 63) == 0) sw[tid >> 6] = local;
    __syncthreads();
    if (tid == 0) out[0] = (sw[0] + sw[1] + sw[2] + sw[3]) / (float)N2;
}

extern "C" void kernel_launch(void* const* d_in, const int* in_sizes, int n_in,
                              void* d_out, int out_size, void* d_ws, size_t ws_size,
                              hipStream_t stream) {
    const float* emb_i = (const float*)d_in[0];
    const float* emb_j = (const float*)d_in[1];

    __bf16* zb      = (__bf16*)d_ws;                                 // 8192*256 bf16 = 4 MB
    float*  g_denom = (float*)((char*)d_ws + (size_t)N2 * D * 2);    // 8192 fp32
    float*  g_pos   = g_denom + N2;                                  // 8192 fp32
    float*  out     = (float*)d_out;

    prep_kernel<<<NHALF / 4, 256, 0, stream>>>(emb_i, emb_j, zb, g_pos, g_denom);
    sim_kernel<<<NT * (NT + 1) / 2, 256, 0, stream>>>(zb, g_denom);
    fin_kernel<<<1, 256, 0, stream>>>(g_denom, g_pos, out);
}

// Round 4
// 130.833 us; speedup vs baseline: 4.3069x; 1.0952x over previous
//
#include <hip/hip_runtime.h>
#include <hip/hip_bf16.h>
#include <math.h>

#define D      256
#define N2     8192
#define NHALF  4096

typedef __bf16 bf16x8_t __attribute__((ext_vector_type(8)));
typedef __bf16 bf16x4_t __attribute__((ext_vector_type(4)));
typedef float  f32x4_t  __attribute__((ext_vector_type(4)));

// ---------------- kernel 1: fused normalize + positives + denom-zero ----------------
__global__ __launch_bounds__(256) void prep_kernel(const float* __restrict__ a,
                                                   const float* __restrict__ b,
                                                   __bf16* __restrict__ zb,
                                                   float* __restrict__ g_pos,
                                                   float* __restrict__ g_denom) {
    const int tid = threadIdx.x;
    const int gt  = blockIdx.x * 256 + tid;
    if (gt < N2) g_denom[gt] = 0.0f;

    const int w = blockIdx.x * 4 + (tid >> 6);  // pair row in [0, NHALF)
    const int l = tid & 63;
    float4 x = ((const float4*)(a + (size_t)w * D))[l];
    float4 y = ((const float4*)(b + (size_t)w * D))[l];
    float sxx = x.x * x.x + x.y * x.y + x.z * x.z + x.w * x.w;
    float syy = y.x * y.x + y.y * y.y + y.z * y.z + y.w * y.w;
    float sxy = x.x * y.x + x.y * y.y + x.z * y.z + x.w * y.w;
    #pragma unroll
    for (int off = 32; off; off >>= 1) {
        sxx += __shfl_xor(sxx, off, 64);
        syy += __shfl_xor(syy, off, 64);
        sxy += __shfl_xor(sxy, off, 64);
    }
    const float rx = 1.0f / fmaxf(sqrtf(sxx), 1e-8f);
    const float ry = 1.0f / fmaxf(sqrtf(syy), 1e-8f);

    bf16x4_t ox, oy;
    ox[0] = (__bf16)(x.x * rx); ox[1] = (__bf16)(x.y * rx);
    ox[2] = (__bf16)(x.z * rx); ox[3] = (__bf16)(x.w * rx);
    oy[0] = (__bf16)(y.x * ry); oy[1] = (__bf16)(y.y * ry);
    oy[2] = (__bf16)(y.z * ry); oy[3] = (__bf16)(y.w * ry);
    *(bf16x4_t*)(zb + (size_t)w * D + l * 4)           = ox;
    *(bf16x4_t*)(zb + (size_t)(w + NHALF) * D + l * 4) = oy;

    if (l == 0) {
        const float p = sxy * rx * ry;
        g_pos[w]         = p;
        g_pos[w + NHALF] = p;
    }
}

// ---------------- kernel 2: balanced wave-work-item sim, reg-resident A, B dbuf ----
// Work item = one wave = (64-row band, chunk of <=16 col-strips of the band's lower-
// triangle range). Bands grouped by 4: group g has g+1 chunks per band, cumulative
// wave count 2g(g+1); total 2112 waves = 528 blocks. No LDS, no barriers. B-strips
// double-buffered in registers so the next strip's L2 loads fly under current MFMAs.
__global__ __launch_bounds__(256, 2) void sim_kernel(const __bf16* __restrict__ zb,
                                                     float* __restrict__ g_denom) {
    const int tid    = threadIdx.x;
    const int wid    = blockIdx.x * 4 + (tid >> 6);
    const int l      = tid & 63;
    const int lane15 = l & 15;
    const int quad   = l >> 4;

    // decode wid -> (band, chunk)
    int g = (int)((sqrtf(2.0f * (float)wid + 1.0f) - 1.0f) * 0.5f);
    while (2 * (g + 1) * (g + 2) <= wid) ++g;
    while (2 * g * (g + 1) > wid) --g;
    const int rem   = wid - 2 * g * (g + 1);
    const int gp1   = g + 1;
    const int boff  = (rem >= gp1) + (rem >= 2 * gp1) + (rem >= 3 * gp1);
    const int band  = 4 * g + boff;
    const int chunk = rem - boff * gp1;
    const int r0    = band * 64;
    const int s0    = chunk * 16;
    const int s1    = min(s0 + 16, 4 * band + 4);
    const int smask = 4 * band;                    // strips >= smask need col<row mask

    // A fragments: 64 rows x K=256 held for the whole chunk
    bf16x8_t af[4][8];
    {
        const __bf16* abase = zb + (size_t)(r0 + lane15) * D + quad * 8;
        #pragma unroll
        for (int mi = 0; mi < 4; ++mi)
            #pragma unroll
            for (int kc = 0; kc < 8; ++kc)
                af[mi][kc] = *(const bf16x8_t*)(abase + (size_t)mi * 16 * D + kc * 32);
    }

    float rs[4] = {0.f, 0.f, 0.f, 0.f};

    bf16x8_t b0[8], b1[8];
    auto loadB = [&](int s, bf16x8_t* dst) {
        const __bf16* bbase = zb + (size_t)(s * 16 + lane15) * D + quad * 8;
        #pragma unroll
        for (int kc = 0; kc < 8; ++kc)
            dst[kc] = *(const bf16x8_t*)(bbase + kc * 32);
    };
    auto compute = [&](int s, const bf16x8_t* bfr) {
        f32x4_t acc[4] = {{0.f,0.f,0.f,0.f},{0.f,0.f,0.f,0.f},{0.f,0.f,0.f,0.f},{0.f,0.f,0.f,0.f}};
        #pragma unroll
        for (int kc = 0; kc < 8; ++kc)
            #pragma unroll
            for (int mi = 0; mi < 4; ++mi)
                acc[mi] = __builtin_amdgcn_mfma_f32_16x16x32_bf16(bfr[kc], af[mi][kc], acc[mi], 0, 0, 0);
        // acc[mi]: S-row = r0+16*mi+lane15 (lane), S-col = s*16+quad*4+t (reg)
        const int  cs     = s * 16;
        const bool masked = (s >= smask);          // wave-uniform
        float cp[4] = {0.f, 0.f, 0.f, 0.f};
        #pragma unroll
        for (int mi = 0; mi < 4; ++mi) {
            const int row = r0 + 16 * mi + lane15;
            #pragma unroll
            for (int t = 0; t < 4; ++t) {
                const int n = cs + quad * 4 + t;
                float e = __expf(2.0f * acc[mi][t]);
                if (masked) e = (n < row) ? e : 0.0f;   // strict lower triangle only
                rs[mi] += e;
                cp[t]  += e;
            }
        }
        #pragma unroll
        for (int off = 1; off < 16; off <<= 1) {
            #pragma unroll
            for (int t = 0; t < 4; ++t) cp[t] += __shfl_xor(cp[t], off, 64);
        }
        if (lane15 == 0) {
            #pragma unroll
            for (int t = 0; t < 4; ++t) atomicAdd(&g_denom[cs + quad * 4 + t], cp[t]);
        }
    };

    loadB(s0, b0);
    int s = s0;
    while (true) {
        if (s + 1 < s1) loadB(s + 1, b1);
        compute(s, b0);
        if (++s >= s1) break;
        if (s + 1 < s1) loadB(s + 1, b0);
        compute(s, b1);
        if (++s >= s1) break;
    }

    // row sums: reduce quad groups, one atomic instr per mi
    #pragma unroll
    for (int mi = 0; mi < 4; ++mi) {
        rs[mi] += __shfl_xor(rs[mi], 16, 64);
        rs[mi] += __shfl_xor(rs[mi], 32, 64);
    }
    if (l < 16) {
        #pragma unroll
        for (int mi = 0; mi < 4; ++mi)
            atomicAdd(&g_denom[r0 + 16 * mi + l], rs[mi]);
    }
}

// ---------------- kernel 3: finalize -> scalar loss ----------------
__global__ __launch_bounds__(256) void fin_kernel(const float* __restrict__ g_denom,
                                                  const float* __restrict__ g_pos,
                                                  float* __restrict__ out) {
    const int tid = threadIdx.x;
    float local = 0.0f;
    for (int k = tid; k < N2; k += 256)
        local += logf(g_denom[k]) - 2.0f * g_pos[k];
    #pragma unroll
    for (int off = 32; off; off >>= 1) local += __shfl_xor(local, off, 64);
    __shared__ float sw[4];
    if ((tid & 63) == 0) sw[tid >> 6] = local;
    __syncthreads();
    if (tid == 0) out[0] = (sw[0] + sw[1] + sw[2] + sw[3]) / (float)N2;
}

extern "C" void kernel_launch(void* const* d_in, const int* in_sizes, int n_in,
                              void* d_out, int out_size, void* d_ws, size_t ws_size,
                              hipStream_t stream) {
    const float* emb_i = (const float*)d_in[0];
    const float* emb_j = (const float*)d_in[1];

    __bf16* zb      = (__bf16*)d_ws;                                 // 4 MB
    float*  g_denom = (float*)((char*)d_ws + (size_t)N2 * D * 2);    // 8192 fp32
    float*  g_pos   = g_denom + N2;                                  // 8192 fp32
    float*  out     = (float*)d_out;

    prep_kernel<<<NHALF / 4, 256, 0, stream>>>(emb_i, emb_j, zb, g_pos, g_denom);
    sim_kernel<<<528, 256, 0, stream>>>(zb, g_denom);   // 2112 waves, uniform chunks
    fin_kernel<<<1, 256, 0, stream>>>(g_denom, g_pos, out);
}